// Round 10
// baseline (276.121 us; speedup 1.0000x reference)
//
#include <hip/hip_runtime.h>
#include <stdint.h>

// B=4, T=2048, C=1024, H=16, D=64.
// Inputs/outputs FP32 (per reference). Internal: bf16 MFMA, fp32 accum.

using u16 = unsigned short;
using u32 = unsigned int;
typedef __attribute__((ext_vector_type(8)))  __bf16 bf16x8;
typedef __attribute__((ext_vector_type(4)))  float  floatx4;
typedef __attribute__((ext_vector_type(16))) float  f32x16;
typedef __attribute__((ext_vector_type(2)))  unsigned int u32x2;

#define QSCALE 0.18033688011112043f   // 0.125 * log2(e), folded into Q projection

__device__ __forceinline__ u16 f2b(float f) {
    union { float f; u32 i; } x; x.f = f;
    return (u16)((x.i + 0x7fffu + ((x.i >> 16) & 1u)) >> 16);
}
__device__ __forceinline__ u32 fbits(float f) { union { float f; u32 i; } x; x.f = f; return x.i; }
// pack two fp32 -> (bf16(b)<<16)|bf16(a) : 2 adds + 1 v_perm
__device__ __forceinline__ u32 pkbf(float a, float b) {
    u32 ia = fbits(a) + 0x8000u, ib = fbits(b) + 0x8000u;
    return __builtin_amdgcn_perm(ib, ia, 0x07060302u);
}
// single-instruction RNE pack: D.lo=bf16(a), D.hi=bf16(b)
__device__ __forceinline__ u32 cvtpk(float a, float b) {
    u32 r; asm("v_cvt_pk_bf16_f32 %0, %1, %2" : "=v"(r) : "v"(a), "v"(b)); return r;
}
__device__ __forceinline__ bf16x8 ld16B(const u16* p) {
    bf16x8 v; __builtin_memcpy(&v, p, 16); return v;
}
__device__ __forceinline__ void async16(const u16* g, u16* l) {
    __builtin_amdgcn_global_load_lds((const __attribute__((address_space(1))) unsigned int*)g,
                                     (__attribute__((address_space(3))) unsigned int*)l,
                                     16, 0, 0);
}

// ---------------- convert fp32 -> bf16 (x + 4 weight matrices) ----------------
__global__ __launch_bounds__(256) void convert_kernel(
    const float* __restrict__ x,
    const float* __restrict__ Wq, const float* __restrict__ Wk,
    const float* __restrict__ Wv, const float* __restrict__ Wo,
    u16* __restrict__ xb, u16* __restrict__ wqb, u16* __restrict__ wkb,
    u16* __restrict__ wvb, u16* __restrict__ wob)
{
    size_t e = ((size_t)blockIdx.x * 256 + threadIdx.x) * 4;
    const float* src; u16* dst; size_t off;
    const size_t XN = (size_t)8 << 20;
    if (e < XN) { src = x; dst = xb; off = e; }
    else {
        size_t k = e - XN;
        int w = (int)(k >> 20);
        off = k & ((1u << 20) - 1);
        src = (w == 0) ? Wq : (w == 1) ? Wk : (w == 2) ? Wv : Wo;
        dst = (w == 0) ? wqb : (w == 1) ? wkb : (w == 2) ? wvb : wob;
    }
    float4 f = *(const float4*)(src + off);
    u32 dws[2] = { pkbf(f.x, f.y), pkbf(f.z, f.w) };
    __builtin_memcpy(dst + off, dws, 8);
}

// ---------------- shared GEMM K-loop: single-buffer 32KB (m97 form), occupancy-first ----------
// acc = A[128 rows m0..] . W[128 rows n0..]^T, K=1024, BK=64, XOR-swizzled LDS.
__device__ __forceinline__ void gemm_loop(const u16* __restrict__ A, const u16* __restrict__ W,
                                          int m0, int n0, floatx4 (&acc)[4][4],
                                          u16* __restrict__ sA, u16* __restrict__ sB)
{
    constexpr int K = 1024;
    const int tid  = threadIdx.x;
    const int wave = tid >> 6, lane = tid & 63;
    const int wr = wave >> 1, wc = wave & 1;
    const int quad = lane >> 4, l15 = lane & 15;

    #pragma unroll
    for (int i = 0; i < 4; ++i)
        #pragma unroll
        for (int j = 0; j < 4; ++j)
            acc[i][j] = (floatx4){0.f, 0.f, 0.f, 0.f};

    const int rstage = lane >> 3;              // 8 rows per async16
    const int gstage = lane & 7;

    #pragma unroll 1
    for (int kb = 0; kb < 16; ++kb) {
        __syncthreads();                       // previous tile fully consumed
        const int k0 = kb * 64;
        #pragma unroll
        for (int j = 0; j < 4; ++j) {
            int r  = wave * 32 + j * 8 + rstage;
            int kg = gstage ^ (r & 7);
            async16(A + (size_t)(m0 + r) * K + k0 + kg * 8, &sA[(wave * 32 + j * 8) * 64]);
            async16(W + (size_t)(n0 + r) * K + k0 + kg * 8, &sB[(wave * 32 + j * 8) * 64]);
        }
        __syncthreads();                       // drains vmcnt (global_load_lds)

        #pragma unroll
        for (int kk = 0; kk < 2; ++kk) {
            bf16x8 af[4], bf[4];
            const int kg = kk * 4 + quad;
            #pragma unroll
            for (int t = 0; t < 4; ++t) {
                int ra = wr * 64 + t * 16 + l15;
                af[t] = ld16B(&sA[ra * 64 + ((kg ^ (ra & 7)) * 8)]);
                int rb = wc * 64 + t * 16 + l15;
                bf[t] = ld16B(&sB[rb * 64 + ((kg ^ (rb & 7)) * 8)]);
            }
            #pragma unroll
            for (int mt = 0; mt < 4; ++mt)
                #pragma unroll
                for (int nt = 0; nt < 4; ++nt)
                    acc[mt][nt] = __builtin_amdgcn_mfma_f32_16x16x32_bf16(af[mt], bf[nt], acc[mt][nt], 0, 0, 0);
        }
    }
}

// ---------------- fused QKV projection ----------------
// Wcat = [3072,1024]. 1-D grid 1536; XCD-partitioned swizzle: each XCD owns 8 m-tiles
// (x slice 2 MB -> L2-resident), n varies per slot.
// z=0: Q row-major * QSCALE; z=1: K row-major; z=2: Vt [bh*64+d][2048].
__global__ __launch_bounds__(256, 3) void qkv_kernel(
    const u16* __restrict__ x, const u16* __restrict__ Wcat,
    const float* __restrict__ bq, const float* __restrict__ bk, const float* __restrict__ bv,
    u16* __restrict__ q, u16* __restrict__ k, u16* __restrict__ vt)
{
    __shared__ __align__(16) u16 sA[128 * 64];
    __shared__ __align__(16) u16 sB[128 * 64];
    const int id = blockIdx.x;
    const int xcd = id & 7, slot = id >> 3;        // 192 slots per XCD
    const int m0 = (xcd * 8 + (slot & 7)) * 128;   // m-tile 0..63
    const int n0 = (slot >> 3) * 128;              // n-tile 0..23
    floatx4 acc[4][4];
    gemm_loop(x, Wcat, m0, n0, acc, sA, sB);

    const int tid = threadIdx.x;
    const int wave = tid >> 6, lane = tid & 63;
    const int wr = wave >> 1, wc = wave & 1;
    const int quad = lane >> 4, l15 = lane & 15;

    const int z = n0 >> 10;
    const float* bb = (z == 0) ? bq : (z == 1) ? bk : bv;
    const float scale = (z == 0) ? QSCALE : 1.0f;
    u16* o = (z == 0) ? q : k;

    #pragma unroll
    for (int nt = 0; nt < 4; ++nt) {
        int col  = n0 + wc * 64 + nt * 16 + l15;   // in [0,3072)
        int c    = col & 1023;
        float bv_ = bb[c];
        #pragma unroll
        for (int mt = 0; mt < 4; ++mt) {
            int row0 = m0 + wr * 64 + mt * 16 + quad * 4;
            if (z == 2) {
                // Vt: addr = ((b*16+h)*64+d)*2048 + t, t=row contiguous -> 8B store
                float v0 = acc[mt][nt][0] + bv_, v1 = acc[mt][nt][1] + bv_;
                float v2 = acc[mt][nt][2] + bv_, v3 = acc[mt][nt][3] + bv_;
                u32 dws[2] = { pkbf(v0, v1), pkbf(v2, v3) };
                int b = row0 >> 11, t0 = row0 & 2047;
                size_t idx = ((size_t)((b * 16 + (c >> 6)) * 64 + (c & 63)) * 2048) + t0;
                __builtin_memcpy(vt + idx, dws, 8);
            } else {
                #pragma unroll
                for (int r = 0; r < 4; ++r) {
                    float v = (acc[mt][nt][r] + bv_) * scale;
                    o[(size_t)(row0 + r) * 1024 + c] = f2b(v);
                }
            }
        }
    }
}

// ---------------- output projection ----------------
__global__ __launch_bounds__(256, 3) void proj_kernel(
    const u16* __restrict__ y, const u16* __restrict__ Wo, const float* __restrict__ bo,
    float* __restrict__ out)
{
    __shared__ __align__(16) u16 sA[128 * 64];
    __shared__ __align__(16) u16 sB[128 * 64];
    const int id = blockIdx.x;
    const int xcd = id & 7, slot = id >> 3;        // 64 slots per XCD
    const int m0 = (xcd * 8 + (slot & 7)) * 128;   // m-tile 0..63
    const int n0 = (slot >> 3) * 128;              // n-tile 0..7
    floatx4 acc[4][4];
    gemm_loop(y, Wo, m0, n0, acc, sA, sB);

    const int tid = threadIdx.x;
    const int wave = tid >> 6, lane = tid & 63;
    const int wr = wave >> 1, wc = wave & 1;
    const int quad = lane >> 4, l15 = lane & 15;

    #pragma unroll
    for (int nt = 0; nt < 4; ++nt) {
        int col = n0 + wc * 64 + nt * 16 + l15;
        float bv_ = bo[col];
        #pragma unroll
        for (int mt = 0; mt < 4; ++mt) {
            int row0 = m0 + wr * 64 + mt * 16 + quad * 4;
            #pragma unroll
            for (int r = 0; r < 4; ++r)
                out[(size_t)(row0 + r) * 1024 + col] = acc[mt][nt][r] + bv_;
        }
    }
}

// ---------------- Flash attention: barrier-free, per-wave private K/V staging --------------
// grid (bh=64, qt=8), block 256 = 4 waves, 2 blocks/CU. Wave owns 64 q-rows (nq=2).
// ZERO __syncthreads in the main loop: each wave owns a private 16KB LDS region
// (K slab [64][64] u16 + V slab [64][64] u16, single-buffered) and stages its own tiles
// via 16 global_load_lds/kt, synced by its own s_waitcnt vmcnt(0). Waves drift into
// different phases -> cross-wave MFMA/VALU/LDS overlap (r0-r3 showed barrier lockstep
// serialized the pipes: MfmaUtil+VALUBusy stuck at ~76% across 3 structures).
// 4x K/V refetch is L2-resident: grid x=bh => all qt-blocks of a bh on XCD bh%8; each
// XCD's 8 bh slabs = 4MB = its L2.
// S^T = mfma_32x32x16(K, Q): C/D col=l31(q), row=(r&3)+8*(r>>2)+4*hf (k).
// P redistribution to PV B-frag = lane<->lane+32 at same l31 (T12).
__global__ __launch_bounds__(256, 2) void attn_kernel(
    const u16* __restrict__ Q, const u16* __restrict__ K,
    const u16* __restrict__ Vt, u16* __restrict__ Y)
{
    const int bh = blockIdx.x, qt = blockIdx.y;
    const int tid = threadIdx.x;
    const int wave = tid >> 6, lane = tid & 63;
    const int hf = lane >> 5, l31 = lane & 31, l7 = l31 & 7;
    const int b = bh >> 4, h = bh & 15;

    // 64KB total: per-wave private 16KB = K slab (4096 u16) + V slab (4096 u16)
    __shared__ __align__(16) u16 smem[32768];
    u16* mK = smem + wave * 8192;
    u16* mV = mK + 4096;

    // Q B-fragments (whole kernel in registers): qf[nq][dc]
    // B-frag: col=l31 (q row), k-dim d = dc*16 + hf*8 + j
    bf16x8 qf[2][4];
    {
        const size_t q0 = (size_t)(b * 2048 + qt * 256 + wave * 64) * 1024 + h * 64 + hf * 8;
        #pragma unroll
        for (int nq = 0; nq < 2; ++nq)
            #pragma unroll
            for (int dc = 0; dc < 4; ++dc)
                qf[nq][dc] = ld16B(Q + q0 + (size_t)(nq * 32 + l31) * 1024 + dc * 16);
    }

    const int r8 = lane >> 3;
    const int g7 = (lane & 7) ^ r8;                 // pre-swizzled global granule
    const u16* kbase = K  + (size_t)(b * 2048 + r8) * 1024 + h * 64 + g7 * 8;
    const u16* vbase = Vt + ((size_t)(bh * 64 + r8)) * 2048 + g7 * 8;

    f32x16 accO[2][2];
    #pragma unroll
    for (int dt = 0; dt < 2; ++dt)
        #pragma unroll
        for (int nq = 0; nq < 2; ++nq)
            #pragma unroll
            for (int i = 0; i < 16; ++i) accO[dt][nq][i] = 0.f;
    float accS[2] = {0.f, 0.f};
    const f32x16 fz = {0.f,0.f,0.f,0.f,0.f,0.f,0.f,0.f,0.f,0.f,0.f,0.f,0.f,0.f,0.f,0.f};

    // prologue: stage tile 0 into private region (16 async16, 8 rows each)
    #pragma unroll
    for (int i = 0; i < 8; ++i) {
        async16(kbase + (size_t)(i * 8) * 1024, mK + i * 512);
        async16(vbase + (size_t)(i * 8) * 2048, mV + i * 512);
    }

    #pragma unroll 1
    for (int kt = 0; kt < 32; ++kt) {
        // own stages complete (vmcnt is per-wave)
        asm volatile("s_waitcnt vmcnt(0)" ::: "memory");
        __builtin_amdgcn_sched_barrier(0);

        // K A-fragments: rows m*32+l31, d-granule (dc*2+hf)^l7
        bf16x8 kfm[2][4];
        #pragma unroll
        for (int m = 0; m < 2; ++m) {
            const int row = m * 32 + l31;
            #pragma unroll
            for (int dc = 0; dc < 4; ++dc)
                kfm[m][dc] = ld16B(&mK[row * 64 + (((dc * 2 + hf) ^ l7) * 8)]);
        }
        asm volatile("s_waitcnt lgkmcnt(0)" ::: "memory");
        __builtin_amdgcn_sched_barrier(0);

        // K buffer consumed -> restage it for kt+1; latency hides under S + c-loop
        if (kt < 31) {
            const u16* kn = kbase + (size_t)((kt + 1) * 64) * 1024;
            #pragma unroll
            for (int i = 0; i < 8; ++i)
                async16(kn + (size_t)(i * 8) * 1024, mK + i * 512);
        }

        // S phase: 16 MFMA, 4 independent chains; fz as C for dc=0 (no zero-init movs)
        f32x16 st[2][2];
        __builtin_amdgcn_s_setprio(1);
        #pragma unroll
        for (int m = 0; m < 2; ++m)
            #pragma unroll
            for (int nq = 0; nq < 2; ++nq)
                st[m][nq] = __builtin_amdgcn_mfma_f32_32x32x16_bf16(kfm[m][0], qf[nq][0], fz, 0, 0, 0);
        #pragma unroll
        for (int dc = 1; dc < 4; ++dc)
            #pragma unroll
            for (int m = 0; m < 2; ++m)
                #pragma unroll
                for (int nq = 0; nq < 2; ++nq)
                    st[m][nq] = __builtin_amdgcn_mfma_f32_32x32x16_bf16(kfm[m][dc], qf[nq][dc], st[m][nq], 0, 0, 0);
        __builtin_amdgcn_s_setprio(0);

        // V A-fragments (read after S: caps live-VGPR; V not yet overwritten)
        bf16x8 vfm[2][4];
        #pragma unroll
        for (int dt = 0; dt < 2; ++dt) {
            const int row = dt * 32 + l31;
            #pragma unroll
            for (int c = 0; c < 4; ++c)
                vfm[dt][c] = ld16B(&mV[row * 64 + (((c * 2 + hf) ^ l7) * 8)]);
        }
        asm volatile("s_waitcnt lgkmcnt(0)" ::: "memory");
        __builtin_amdgcn_sched_barrier(0);

        // V buffer consumed -> restage; latency hides under c-loop
        if (kt < 31) {
            const u16* vn = vbase + (size_t)((kt + 1) * 64);
            #pragma unroll
            for (int i = 0; i < 8; ++i)
                async16(vn + (size_t)(i * 8) * 2048, mV + i * 512);
        }

        // exp2 -> pack -> permlane32_swap -> PV, per (c, nq); rowsum via f32 adds
        #pragma unroll
        for (int c = 0; c < 4; ++c) {
            const int m = c >> 1, r0 = (c & 1) * 8;
            #pragma unroll
            for (int nq = 0; nq < 2; ++nq) {
                float e0 = __builtin_amdgcn_exp2f(st[m][nq][r0 + 0]);
                float e1 = __builtin_amdgcn_exp2f(st[m][nq][r0 + 1]);
                float e2 = __builtin_amdgcn_exp2f(st[m][nq][r0 + 2]);
                float e3 = __builtin_amdgcn_exp2f(st[m][nq][r0 + 3]);
                float e4 = __builtin_amdgcn_exp2f(st[m][nq][r0 + 4]);
                float e5 = __builtin_amdgcn_exp2f(st[m][nq][r0 + 5]);
                float e6 = __builtin_amdgcn_exp2f(st[m][nq][r0 + 6]);
                float e7 = __builtin_amdgcn_exp2f(st[m][nq][r0 + 7]);
                accS[nq] += ((e0 + e1) + (e2 + e3)) + ((e4 + e5) + (e6 + e7));
                u32 Ua = cvtpk(e0, e1), Ub = cvtpk(e2, e3);
                u32 Va = cvtpk(e4, e5), Vb = cvtpk(e6, e7);
                u32x2 s0 = __builtin_amdgcn_permlane32_swap(Ua, Va, false, false);
                u32x2 s1 = __builtin_amdgcn_permlane32_swap(Ub, Vb, false, false);
                u32 dws[4] = { s0.x, s1.x, s0.y, s1.y };
                bf16x8 pB; __builtin_memcpy(&pB, dws, 16);
                __builtin_amdgcn_s_setprio(1);
                accO[0][nq] = __builtin_amdgcn_mfma_f32_32x32x16_bf16(vfm[0][c], pB, accO[0][nq], 0, 0, 0);
                accO[1][nq] = __builtin_amdgcn_mfma_f32_32x32x16_bf16(vfm[1][c], pB, accO[1][nq], 0, 0, 0);
                __builtin_amdgcn_s_setprio(0);
            }
        }
    }

    // rowsum: lane holds k-halves with bit2==hf; partner is lane^32
    #pragma unroll
    for (int nq = 0; nq < 2; ++nq) accS[nq] += __shfl_xor(accS[nq], 32);
    const float inv0 = 1.f / accS[0], inv1 = 1.f / accS[1];

    // epilogue: normalize, transpose O^T->O via the wave's private 8KB region (reuses mK)
    u16* ep = mK;   // 64 rows(q) x 64 cols(d), 16B-granule XOR swizzle
    #pragma unroll
    for (int nq = 0; nq < 2; ++nq) {
        const float inv = nq ? inv1 : inv0;
        const int row = nq * 32 + l31;
        #pragma unroll
        for (int dt = 0; dt < 2; ++dt)
            #pragma unroll
            for (int rq = 0; rq < 4; ++rq) {
                // accO reg r=rq*4+e -> d = dt*32 + rq*8 + 4*hf + e, q = row
                float v0 = accO[dt][nq][rq * 4 + 0] * inv;
                float v1 = accO[dt][nq][rq * 4 + 1] * inv;
                float v2 = accO[dt][nq][rq * 4 + 2] * inv;
                float v3 = accO[dt][nq][rq * 4 + 3] * inv;
                u32 dws[2] = { cvtpk(v0, v1), cvtpk(v2, v3) };
                const int g = dt * 4 + rq;
                __builtin_memcpy((char*)ep + row * 128 + ((g ^ l7) * 16) + hf * 8, dws, 8);
            }
    }
    // wave-private region: compiler orders ds write->read via lgkmcnt, no barrier needed
    const int rl = lane >> 3, cl = lane & 7;
    #pragma unroll
    for (int pass = 0; pass < 8; ++pass) {
        const int row = pass * 8 + rl;
        bf16x8 vrow = ld16B((const u16*)((const char*)ep + row * 128 + ((cl ^ (row & 7)) * 16)));
        const int t = qt * 256 + wave * 64 + row;
        __builtin_memcpy(Y + ((size_t)(b * 2048 + t)) * 1024 + h * 64 + cl * 8, &vrow, 16);
    }
}

// ---------------- launch ----------------
extern "C" void kernel_launch(void* const* d_in, const int* in_sizes, int n_in,
                              void* d_out, int out_size, void* d_ws, size_t ws_size,
                              hipStream_t stream)
{
    const float* x  = (const float*)d_in[0];
    const float* Wq = (const float*)d_in[1];
    const float* bq = (const float*)d_in[2];
    const float* Wk = (const float*)d_in[3];
    const float* bk = (const float*)d_in[4];
    const float* Wv = (const float*)d_in[5];
    const float* bv = (const float*)d_in[6];
    const float* Wo = (const float*)d_in[7];
    const float* bo = (const float*)d_in[8];
    float* out = (float*)d_out;

    const size_t NTOK = (size_t)8192 * 1024;
    const size_t WN   = (size_t)1024 * 1024;
    u16* xb  = (u16*)d_ws;
    u16* wqb = xb + NTOK;     // wq, wk, wv contiguous => [3072,1024] fused weight
    u16* wkb = wqb + WN;
    u16* wvb = wkb + WN;
    u16* wob = wvb + WN;
    u16* q   = wob + WN;
    u16* k   = q + NTOK;
    u16* vt  = k + NTOK;
    u16* y   = vt + NTOK;

    convert_kernel<<<dim3(12288), 256, 0, stream>>>(x, Wq, Wk, Wv, Wo, xb, wqb, wkb, wvb, wob);
    qkv_kernel<<<dim3(1536), 256, 0, stream>>>(xb, wqb, bq, bk, bv, q, k, vt);
    attn_kernel<<<dim3(64, 8), 256, 0, stream>>>(q, k, vt, y);
    proj_kernel<<<dim3(512), 256, 0, stream>>>(y, wob, bo, out);
}

// Round 12
// 274.575 us; speedup vs baseline: 1.0056x; 1.0056x over previous
//
#include <hip/hip_runtime.h>
#include <stdint.h>

// B=4, T=2048, C=1024, H=16, D=64.
// Inputs/outputs FP32 (per reference). Internal: bf16 MFMA, fp32 accum.

using u16 = unsigned short;
using u32 = unsigned int;
typedef __attribute__((ext_vector_type(8)))  __bf16 bf16x8;
typedef __attribute__((ext_vector_type(4)))  float  floatx4;
typedef __attribute__((ext_vector_type(16))) float  f32x16;
typedef __attribute__((ext_vector_type(2)))  unsigned int u32x2;

#define QSCALE 0.18033688011112043f   // 0.125 * log2(e), folded into Q projection

__device__ __forceinline__ u16 f2b(float f) {
    union { float f; u32 i; } x; x.f = f;
    return (u16)((x.i + 0x7fffu + ((x.i >> 16) & 1u)) >> 16);
}
__device__ __forceinline__ u32 fbits(float f) { union { float f; u32 i; } x; x.f = f; return x.i; }
// pack two fp32 -> (bf16(b)<<16)|bf16(a) : 2 adds + 1 v_perm
__device__ __forceinline__ u32 pkbf(float a, float b) {
    u32 ia = fbits(a) + 0x8000u, ib = fbits(b) + 0x8000u;
    return __builtin_amdgcn_perm(ib, ia, 0x07060302u);
}
// single-instruction RNE pack: D.lo=bf16(a), D.hi=bf16(b)
__device__ __forceinline__ u32 cvtpk(float a, float b) {
    u32 r; asm("v_cvt_pk_bf16_f32 %0, %1, %2" : "=v"(r) : "v"(a), "v"(b)); return r;
}
__device__ __forceinline__ bf16x8 ld16B(const u16* p) {
    bf16x8 v; __builtin_memcpy(&v, p, 16); return v;
}
__device__ __forceinline__ void async16(const u16* g, u16* l) {
    __builtin_amdgcn_global_load_lds((const __attribute__((address_space(1))) unsigned int*)g,
                                     (__attribute__((address_space(3))) unsigned int*)l,
                                     16, 0, 0);
}

// ---------------- convert fp32 -> bf16 (x + 4 weight matrices) ----------------
__global__ __launch_bounds__(256) void convert_kernel(
    const float* __restrict__ x,
    const float* __restrict__ Wq, const float* __restrict__ Wk,
    const float* __restrict__ Wv, const float* __restrict__ Wo,
    u16* __restrict__ xb, u16* __restrict__ wqb, u16* __restrict__ wkb,
    u16* __restrict__ wvb, u16* __restrict__ wob)
{
    size_t e = ((size_t)blockIdx.x * 256 + threadIdx.x) * 4;
    const float* src; u16* dst; size_t off;
    const size_t XN = (size_t)8 << 20;
    if (e < XN) { src = x; dst = xb; off = e; }
    else {
        size_t k = e - XN;
        int w = (int)(k >> 20);
        off = k & ((1u << 20) - 1);
        src = (w == 0) ? Wq : (w == 1) ? Wk : (w == 2) ? Wv : Wo;
        dst = (w == 0) ? wqb : (w == 1) ? wkb : (w == 2) ? wvb : wob;
    }
    float4 f = *(const float4*)(src + off);
    u32 dws[2] = { pkbf(f.x, f.y), pkbf(f.z, f.w) };
    __builtin_memcpy(dst + off, dws, 8);
}

// ---------------- shared GEMM K-loop: single-buffer 32KB (m97 form), occupancy-first ----------
// acc = A[128 rows m0..] . W[128 rows n0..]^T, K=1024, BK=64, XOR-swizzled LDS.
__device__ __forceinline__ void gemm_loop(const u16* __restrict__ A, const u16* __restrict__ W,
                                          int m0, int n0, floatx4 (&acc)[4][4],
                                          u16* __restrict__ sA, u16* __restrict__ sB)
{
    constexpr int K = 1024;
    const int tid  = threadIdx.x;
    const int wave = tid >> 6, lane = tid & 63;
    const int wr = wave >> 1, wc = wave & 1;
    const int quad = lane >> 4, l15 = lane & 15;

    #pragma unroll
    for (int i = 0; i < 4; ++i)
        #pragma unroll
        for (int j = 0; j < 4; ++j)
            acc[i][j] = (floatx4){0.f, 0.f, 0.f, 0.f};

    const int rstage = lane >> 3;              // 8 rows per async16
    const int gstage = lane & 7;

    #pragma unroll 1
    for (int kb = 0; kb < 16; ++kb) {
        __syncthreads();                       // previous tile fully consumed
        const int k0 = kb * 64;
        #pragma unroll
        for (int j = 0; j < 4; ++j) {
            int r  = wave * 32 + j * 8 + rstage;
            int kg = gstage ^ (r & 7);
            async16(A + (size_t)(m0 + r) * K + k0 + kg * 8, &sA[(wave * 32 + j * 8) * 64]);
            async16(W + (size_t)(n0 + r) * K + k0 + kg * 8, &sB[(wave * 32 + j * 8) * 64]);
        }
        __syncthreads();                       // drains vmcnt (global_load_lds)

        #pragma unroll
        for (int kk = 0; kk < 2; ++kk) {
            bf16x8 af[4], bf[4];
            const int kg = kk * 4 + quad;
            #pragma unroll
            for (int t = 0; t < 4; ++t) {
                int ra = wr * 64 + t * 16 + l15;
                af[t] = ld16B(&sA[ra * 64 + ((kg ^ (ra & 7)) * 8)]);
                int rb = wc * 64 + t * 16 + l15;
                bf[t] = ld16B(&sB[rb * 64 + ((kg ^ (rb & 7)) * 8)]);
            }
            #pragma unroll
            for (int mt = 0; mt < 4; ++mt)
                #pragma unroll
                for (int nt = 0; nt < 4; ++nt)
                    acc[mt][nt] = __builtin_amdgcn_mfma_f32_16x16x32_bf16(af[mt], bf[nt], acc[mt][nt], 0, 0, 0);
        }
    }
}

// ---------------- fused QKV projection ----------------
// Wcat = [3072,1024]. 1-D grid 1536; XCD-partitioned swizzle: each XCD owns 8 m-tiles
// (x slice 2 MB -> L2-resident), n varies per slot.
// z=0: Q row-major * QSCALE; z=1: K row-major; z=2: Vt [bh*64+d][2048].
__global__ __launch_bounds__(256, 3) void qkv_kernel(
    const u16* __restrict__ x, const u16* __restrict__ Wcat,
    const float* __restrict__ bq, const float* __restrict__ bk, const float* __restrict__ bv,
    u16* __restrict__ q, u16* __restrict__ k, u16* __restrict__ vt)
{
    __shared__ __align__(16) u16 sA[128 * 64];
    __shared__ __align__(16) u16 sB[128 * 64];
    const int id = blockIdx.x;
    const int xcd = id & 7, slot = id >> 3;        // 192 slots per XCD
    const int m0 = (xcd * 8 + (slot & 7)) * 128;   // m-tile 0..63
    const int n0 = (slot >> 3) * 128;              // n-tile 0..23
    floatx4 acc[4][4];
    gemm_loop(x, Wcat, m0, n0, acc, sA, sB);

    const int tid = threadIdx.x;
    const int wave = tid >> 6, lane = tid & 63;
    const int wr = wave >> 1, wc = wave & 1;
    const int quad = lane >> 4, l15 = lane & 15;

    const int z = n0 >> 10;
    const float* bb = (z == 0) ? bq : (z == 1) ? bk : bv;
    const float scale = (z == 0) ? QSCALE : 1.0f;
    u16* o = (z == 0) ? q : k;

    #pragma unroll
    for (int nt = 0; nt < 4; ++nt) {
        int col  = n0 + wc * 64 + nt * 16 + l15;   // in [0,3072)
        int c    = col & 1023;
        float bv_ = bb[c];
        #pragma unroll
        for (int mt = 0; mt < 4; ++mt) {
            int row0 = m0 + wr * 64 + mt * 16 + quad * 4;
            if (z == 2) {
                // Vt: addr = ((b*16+h)*64+d)*2048 + t, t=row contiguous -> 8B store
                float v0 = acc[mt][nt][0] + bv_, v1 = acc[mt][nt][1] + bv_;
                float v2 = acc[mt][nt][2] + bv_, v3 = acc[mt][nt][3] + bv_;
                u32 dws[2] = { pkbf(v0, v1), pkbf(v2, v3) };
                int b = row0 >> 11, t0 = row0 & 2047;
                size_t idx = ((size_t)((b * 16 + (c >> 6)) * 64 + (c & 63)) * 2048) + t0;
                __builtin_memcpy(vt + idx, dws, 8);
            } else {
                #pragma unroll
                for (int r = 0; r < 4; ++r) {
                    float v = (acc[mt][nt][r] + bv_) * scale;
                    o[(size_t)(row0 + r) * 1024 + c] = f2b(v);
                }
            }
        }
    }
}

// ---------------- output projection ----------------
__global__ __launch_bounds__(256, 3) void proj_kernel(
    const u16* __restrict__ y, const u16* __restrict__ Wo, const float* __restrict__ bo,
    float* __restrict__ out)
{
    __shared__ __align__(16) u16 sA[128 * 64];
    __shared__ __align__(16) u16 sB[128 * 64];
    const int id = blockIdx.x;
    const int xcd = id & 7, slot = id >> 3;        // 64 slots per XCD
    const int m0 = (xcd * 8 + (slot & 7)) * 128;   // m-tile 0..63
    const int n0 = (slot >> 3) * 128;              // n-tile 0..7
    floatx4 acc[4][4];
    gemm_loop(y, Wo, m0, n0, acc, sA, sB);

    const int tid = threadIdx.x;
    const int wave = tid >> 6, lane = tid & 63;
    const int wr = wave >> 1, wc = wave & 1;
    const int quad = lane >> 4, l15 = lane & 15;

    #pragma unroll
    for (int nt = 0; nt < 4; ++nt) {
        int col = n0 + wc * 64 + nt * 16 + l15;
        float bv_ = bo[col];
        #pragma unroll
        for (int mt = 0; mt < 4; ++mt) {
            int row0 = m0 + wr * 64 + mt * 16 + quad * 4;
            #pragma unroll
            for (int r = 0; r < 4; ++r)
                out[(size_t)(row0 + r) * 1024 + col] = acc[mt][nt][r] + bv_;
        }
    }
}

// ---------------- Flash attention: r1 structure + V register-direct from L2 ---------------
// grid (bh=64, qt=8), block 256 = 4 waves, 2 blocks/CU. Wave owns 64 q-rows (nq=2).
// r0/r3/r10 falsified P-LDS-cost, occupancy, and barrier-lockstep theories; common wall:
// shared per-CU LDS pipe queuing (stage-writes + K,V fragment reads all on one pipe).
// Fix: V A-fragments load DIRECTLY global->reg (Vt is L2-resident: grid x=bh pins each
// bh's 1MB slab to XCD bh%8). Halves LDS traffic (writes 16->8KB, reads 64->32KB per
// block-kt); V's L2 latency hides under the S-MFMA phase. K stays LDS-staged (shared,
// double-buffered, XOR-swizzled; one barrier per kt).
// S^T = mfma_32x32x16(K, Q): C/D col=l31(q), row=(r&3)+8*(r>>2)+4*hf (k).
// P redistribution to PV B-frag = lane<->lane+32 at same l31 (T12).
__global__ __launch_bounds__(256, 2) void attn_kernel(
    const u16* __restrict__ Q, const u16* __restrict__ K,
    const u16* __restrict__ Vt, u16* __restrict__ Y)
{
    const int bh = blockIdx.x, qt = blockIdx.y;
    const int tid = threadIdx.x;
    const int wave = tid >> 6, lane = tid & 63;
    const int hf = lane >> 5, l31 = lane & 31, l7 = l31 & 7;
    const int b = bh >> 4, h = bh & 15;

    // 32KB: [Kbuf0 | Kbuf1] = 16KB K double-buffer; epilogue reuses full 32KB as 4x8KB.
    __shared__ __align__(16) u16 smem[16384];

    // Q B-fragments (whole kernel in registers): qf[nq][dc]
    // B-frag: col=l31 (q row), k-dim d = dc*16 + hf*8 + j
    bf16x8 qf[2][4];
    {
        const size_t q0 = (size_t)(b * 2048 + qt * 256 + wave * 64) * 1024 + h * 64 + hf * 8;
        #pragma unroll
        for (int nq = 0; nq < 2; ++nq)
            #pragma unroll
            for (int dc = 0; dc < 4; ++dc)
                qf[nq][dc] = ld16B(Q + q0 + (size_t)(nq * 32 + l31) * 1024 + dc * 16);
    }

    const int r8 = lane >> 3;
    const int g7 = (lane & 7) ^ r8;                 // pre-swizzled global granule (K staging)
    const u16* ksrc = K + (size_t)(b * 2048 + wave * 16 + r8) * 1024 + h * 64 + g7 * 8;
    // V direct-load base: lane reads 16B at row (bh*64 + dt*32 + l31), col kt*64 + c*16 + hf*8
    const u16* vbase = Vt + (size_t)(bh * 64 + l31) * 2048 + hf * 8;

    f32x16 accO[2][2];
    #pragma unroll
    for (int dt = 0; dt < 2; ++dt)
        #pragma unroll
        for (int nq = 0; nq < 2; ++nq)
            #pragma unroll
            for (int i = 0; i < 16; ++i) accO[dt][nq][i] = 0.f;
    float accS[2] = {0.f, 0.f};
    const f32x16 fz = {0.f,0.f,0.f,0.f,0.f,0.f,0.f,0.f,0.f,0.f,0.f,0.f,0.f,0.f,0.f,0.f};

    // prologue: stage K tile 0 into buf 0 (2 async16 per wave, 16 rows)
    {
        u16* dK = smem + wave * 1024;
        async16(ksrc,            dK);
        async16(ksrc + 8 * 1024, dK + 512);
    }
    __syncthreads();

    #pragma unroll 1
    for (int kt = 0; kt < 32; ++kt) {
        const int cur = kt & 1;

        // V A-fragments: issue FIRST (oldest vmcnt slots) -> PV's wait leaves staging in flight
        bf16x8 vfm[2][4];
        {
            const u16* vbl = vbase + kt * 64;
            #pragma unroll
            for (int dt = 0; dt < 2; ++dt)
                #pragma unroll
                for (int c = 0; c < 4; ++c)
                    vfm[dt][c] = ld16B(vbl + (size_t)dt * 32 * 2048 + c * 16);
        }

        // stage K for kt+1 into the other buffer (completes at end-of-kt barrier)
        if (kt < 31) {
            u16* dK = smem + (cur ^ 1) * 4096 + wave * 1024;
            const u16* ks = ksrc + (size_t)(kt + 1) * 64 * 1024;
            async16(ks,            dK);
            async16(ks + 8 * 1024, dK + 512);
        }

        // K A-fragments from LDS: rows m*32+l31, d-granule (dc*2+hf)^l7
        const u16* bK = smem + cur * 4096;
        bf16x8 kfm[2][4];
        #pragma unroll
        for (int m = 0; m < 2; ++m) {
            const int row = m * 32 + l31;
            #pragma unroll
            for (int dc = 0; dc < 4; ++dc)
                kfm[m][dc] = ld16B(&bK[row * 64 + (((dc * 2 + hf) ^ l7) * 8)]);
        }

        // S phase: 16 MFMA, 4 independent chains; fz as C for dc=0 (no zero-init movs)
        f32x16 st[2][2];
        __builtin_amdgcn_s_setprio(1);
        #pragma unroll
        for (int m = 0; m < 2; ++m)
            #pragma unroll
            for (int nq = 0; nq < 2; ++nq)
                st[m][nq] = __builtin_amdgcn_mfma_f32_32x32x16_bf16(kfm[m][0], qf[nq][0], fz, 0, 0, 0);
        #pragma unroll
        for (int dc = 1; dc < 4; ++dc)
            #pragma unroll
            for (int m = 0; m < 2; ++m)
                #pragma unroll
                for (int nq = 0; nq < 2; ++nq)
                    st[m][nq] = __builtin_amdgcn_mfma_f32_32x32x16_bf16(kfm[m][dc], qf[nq][dc], st[m][nq], 0, 0, 0);
        __builtin_amdgcn_s_setprio(0);

        // exp2 -> pack -> permlane32_swap -> PV, per (c, nq); rowsum via f32 adds
        #pragma unroll
        for (int c = 0; c < 4; ++c) {
            const int m = c >> 1, r0 = (c & 1) * 8;
            #pragma unroll
            for (int nq = 0; nq < 2; ++nq) {
                float e0 = __builtin_amdgcn_exp2f(st[m][nq][r0 + 0]);
                float e1 = __builtin_amdgcn_exp2f(st[m][nq][r0 + 1]);
                float e2 = __builtin_amdgcn_exp2f(st[m][nq][r0 + 2]);
                float e3 = __builtin_amdgcn_exp2f(st[m][nq][r0 + 3]);
                float e4 = __builtin_amdgcn_exp2f(st[m][nq][r0 + 4]);
                float e5 = __builtin_amdgcn_exp2f(st[m][nq][r0 + 5]);
                float e6 = __builtin_amdgcn_exp2f(st[m][nq][r0 + 6]);
                float e7 = __builtin_amdgcn_exp2f(st[m][nq][r0 + 7]);
                accS[nq] += ((e0 + e1) + (e2 + e3)) + ((e4 + e5) + (e6 + e7));
                u32 Ua = cvtpk(e0, e1), Ub = cvtpk(e2, e3);
                u32 Va = cvtpk(e4, e5), Vb = cvtpk(e6, e7);
                u32x2 s0 = __builtin_amdgcn_permlane32_swap(Ua, Va, false, false);
                u32x2 s1 = __builtin_amdgcn_permlane32_swap(Ub, Vb, false, false);
                u32 dws[4] = { s0.x, s1.x, s0.y, s1.y };
                bf16x8 pB; __builtin_memcpy(&pB, dws, 16);
                __builtin_amdgcn_s_setprio(1);
                accO[0][nq] = __builtin_amdgcn_mfma_f32_32x32x16_bf16(vfm[0][c], pB, accO[0][nq], 0, 0, 0);
                accO[1][nq] = __builtin_amdgcn_mfma_f32_32x32x16_bf16(vfm[1][c], pB, accO[1][nq], 0, 0, 0);
                __builtin_amdgcn_s_setprio(0);
            }
        }
        __syncthreads();   // K staging complete + buf consumed by all waves
    }

    // rowsum: lane holds k-halves with bit2==hf; partner is lane^32
    #pragma unroll
    for (int nq = 0; nq < 2; ++nq) accS[nq] += __shfl_xor(accS[nq], 32);
    const float inv0 = 1.f / accS[0], inv1 = 1.f / accS[1];

    // epilogue: normalize, transpose O^T->O via per-wave 8KB LDS region (reuses K bufs;
    // safe: final loop barrier means no wave still reads sK)
    u16* ep = smem + wave * 4096;   // 64 rows(q) x 64 cols(d), 16B-granule XOR swizzle
    #pragma unroll
    for (int nq = 0; nq < 2; ++nq) {
        const float inv = nq ? inv1 : inv0;
        const int row = nq * 32 + l31;
        #pragma unroll
        for (int dt = 0; dt < 2; ++dt)
            #pragma unroll
            for (int rq = 0; rq < 4; ++rq) {
                // accO reg r=rq*4+e -> d = dt*32 + rq*8 + 4*hf + e, q = row
                float v0 = accO[dt][nq][rq * 4 + 0] * inv;
                float v1 = accO[dt][nq][rq * 4 + 1] * inv;
                float v2 = accO[dt][nq][rq * 4 + 2] * inv;
                float v3 = accO[dt][nq][rq * 4 + 3] * inv;
                u32 dws[2] = { cvtpk(v0, v1), cvtpk(v2, v3) };
                const int g = dt * 4 + rq;
                __builtin_memcpy((char*)ep + row * 128 + ((g ^ l7) * 16) + hf * 8, dws, 8);
            }
    }
    // wave-private region: compiler orders ds write->read via lgkmcnt, no barrier needed
    const int rl = lane >> 3, cl = lane & 7;
    #pragma unroll
    for (int pass = 0; pass < 8; ++pass) {
        const int row = pass * 8 + rl;
        bf16x8 vrow = ld16B((const u16*)((const char*)ep + row * 128 + ((cl ^ (row & 7)) * 16)));
        const int t = qt * 256 + wave * 64 + row;
        __builtin_memcpy(Y + ((size_t)(b * 2048 + t)) * 1024 + h * 64 + cl * 8, &vrow, 16);
    }
}

// ---------------- launch ----------------
extern "C" void kernel_launch(void* const* d_in, const int* in_sizes, int n_in,
                              void* d_out, int out_size, void* d_ws, size_t ws_size,
                              hipStream_t stream)
{
    const float* x  = (const float*)d_in[0];
    const float* Wq = (const float*)d_in[1];
    const float* bq = (const float*)d_in[2];
    const float* Wk = (const float*)d_in[3];
    const float* bk = (const float*)d_in[4];
    const float* Wv = (const float*)d_in[5];
    const float* bv = (const float*)d_in[6];
    const float* Wo = (const float*)d_in[7];
    const float* bo = (const float*)d_in[8];
    float* out = (float*)d_out;

    const size_t NTOK = (size_t)8192 * 1024;
    const size_t WN   = (size_t)1024 * 1024;
    u16* xb  = (u16*)d_ws;
    u16* wqb = xb + NTOK;     // wq, wk, wv contiguous => [3072,1024] fused weight
    u16* wkb = wqb + WN;
    u16* wvb = wkb + WN;
    u16* wob = wvb + WN;
    u16* q   = wob + WN;
    u16* k   = q + NTOK;
    u16* vt  = k + NTOK;
    u16* y   = vt + NTOK;

    convert_kernel<<<dim3(12288), 256, 0, stream>>>(x, Wq, Wk, Wv, Wo, xb, wqb, wkb, wvb, wob);
    qkv_kernel<<<dim3(1536), 256, 0, stream>>>(xb, wqb, bq, bk, bv, q, k, vt);
    attn_kernel<<<dim3(64, 8), 256, 0, stream>>>(q, k, vt, y);
    proj_kernel<<<dim3(512), 256, 0, stream>>>(y, wob, bo, out);
}

// Round 17
// 244.837 us; speedup vs baseline: 1.1278x; 1.1215x over previous
//
#include <hip/hip_runtime.h>
#include <stdint.h>

// B=4, T=2048, C=1024, H=16, D=64.
// Inputs/outputs FP32 (per reference). Internal: bf16 MFMA, fp32 accum.

using u16 = unsigned short;
using u32 = unsigned int;
typedef __attribute__((ext_vector_type(8)))  __bf16 bf16x8;
typedef __attribute__((ext_vector_type(4)))  float  floatx4;
typedef __attribute__((ext_vector_type(16))) float  f32x16;
typedef __attribute__((ext_vector_type(2)))  unsigned int u32x2;

#define QSCALE 0.18033688011112043f   // 0.125 * log2(e), folded into Q projection

__device__ __forceinline__ u16 f2b(float f) {
    union { float f; u32 i; } x; x.f = f;
    return (u16)((x.i + 0x7fffu + ((x.i >> 16) & 1u)) >> 16);
}
__device__ __forceinline__ u32 fbits(float f) { union { float f; u32 i; } x; x.f = f; return x.i; }
// pack two fp32 -> (bf16(b)<<16)|bf16(a) : 2 adds + 1 v_perm
__device__ __forceinline__ u32 pkbf(float a, float b) {
    u32 ia = fbits(a) + 0x8000u, ib = fbits(b) + 0x8000u;
    return __builtin_amdgcn_perm(ib, ia, 0x07060302u);
}
// single-instruction RNE pack: D.lo=bf16(a), D.hi=bf16(b)
__device__ __forceinline__ u32 cvtpk(float a, float b) {
    u32 r; asm("v_cvt_pk_bf16_f32 %0, %1, %2" : "=v"(r) : "v"(a), "v"(b)); return r;
}
__device__ __forceinline__ bf16x8 ld16B(const u16* p) {
    bf16x8 v; __builtin_memcpy(&v, p, 16); return v;
}
__device__ __forceinline__ void async16(const u16* g, u16* l) {
    __builtin_amdgcn_global_load_lds((const __attribute__((address_space(1))) unsigned int*)g,
                                     (__attribute__((address_space(3))) unsigned int*)l,
                                     16, 0, 0);
}

// ---------------- convert fp32 -> bf16 (x + 4 weight matrices) ----------------
__global__ __launch_bounds__(256) void convert_kernel(
    const float* __restrict__ x,
    const float* __restrict__ Wq, const float* __restrict__ Wk,
    const float* __restrict__ Wv, const float* __restrict__ Wo,
    u16* __restrict__ xb, u16* __restrict__ wqb, u16* __restrict__ wkb,
    u16* __restrict__ wvb, u16* __restrict__ wob)
{
    size_t e = ((size_t)blockIdx.x * 256 + threadIdx.x) * 4;
    const float* src; u16* dst; size_t off;
    const size_t XN = (size_t)8 << 20;
    if (e < XN) { src = x; dst = xb; off = e; }
    else {
        size_t k = e - XN;
        int w = (int)(k >> 20);
        off = k & ((1u << 20) - 1);
        src = (w == 0) ? Wq : (w == 1) ? Wk : (w == 2) ? Wv : Wo;
        dst = (w == 0) ? wqb : (w == 1) ? wkb : (w == 2) ? wvb : wob;
    }
    float4 f = *(const float4*)(src + off);
    u32 dws[2] = { pkbf(f.x, f.y), pkbf(f.z, f.w) };
    __builtin_memcpy(dst + off, dws, 8);
}

// ---------------- shared GEMM K-loop: single-buffer 32KB (m97 form), occupancy-first ----------
// acc = A[128 rows m0..] . W[128 rows n0..]^T, K=1024, BK=64, XOR-swizzled LDS.
__device__ __forceinline__ void gemm_loop(const u16* __restrict__ A, const u16* __restrict__ W,
                                          int m0, int n0, floatx4 (&acc)[4][4],
                                          u16* __restrict__ sA, u16* __restrict__ sB)
{
    constexpr int K = 1024;
    const int tid  = threadIdx.x;
    const int wave = tid >> 6, lane = tid & 63;
    const int wr = wave >> 1, wc = wave & 1;
    const int quad = lane >> 4, l15 = lane & 15;

    #pragma unroll
    for (int i = 0; i < 4; ++i)
        #pragma unroll
        for (int j = 0; j < 4; ++j)
            acc[i][j] = (floatx4){0.f, 0.f, 0.f, 0.f};

    const int rstage = lane >> 3;              // 8 rows per async16
    const int gstage = lane & 7;

    #pragma unroll 1
    for (int kb = 0; kb < 16; ++kb) {
        __syncthreads();                       // previous tile fully consumed
        const int k0 = kb * 64;
        #pragma unroll
        for (int j = 0; j < 4; ++j) {
            int r  = wave * 32 + j * 8 + rstage;
            int kg = gstage ^ (r & 7);
            async16(A + (size_t)(m0 + r) * K + k0 + kg * 8, &sA[(wave * 32 + j * 8) * 64]);
            async16(W + (size_t)(n0 + r) * K + k0 + kg * 8, &sB[(wave * 32 + j * 8) * 64]);
        }
        __syncthreads();                       // drains vmcnt (global_load_lds)

        #pragma unroll
        for (int kk = 0; kk < 2; ++kk) {
            bf16x8 af[4], bf[4];
            const int kg = kk * 4 + quad;
            #pragma unroll
            for (int t = 0; t < 4; ++t) {
                int ra = wr * 64 + t * 16 + l15;
                af[t] = ld16B(&sA[ra * 64 + ((kg ^ (ra & 7)) * 8)]);
                int rb = wc * 64 + t * 16 + l15;
                bf[t] = ld16B(&sB[rb * 64 + ((kg ^ (rb & 7)) * 8)]);
            }
            #pragma unroll
            for (int mt = 0; mt < 4; ++mt)
                #pragma unroll
                for (int nt = 0; nt < 4; ++nt)
                    acc[mt][nt] = __builtin_amdgcn_mfma_f32_16x16x32_bf16(af[mt], bf[nt], acc[mt][nt], 0, 0, 0);
        }
    }
}

// ---------------- fused QKV projection ----------------
// Wcat = [3072,1024]. 1-D grid 1536; XCD-partitioned swizzle: each XCD owns 8 m-tiles
// (x slice 2 MB -> L2-resident), n varies per slot.
// z=0: Q row-major * QSCALE; z=1: K row-major; z=2: Vt [bh*64+d][2048].
__global__ __launch_bounds__(256, 3) void qkv_kernel(
    const u16* __restrict__ x, const u16* __restrict__ Wcat,
    const float* __restrict__ bq, const float* __restrict__ bk, const float* __restrict__ bv,
    u16* __restrict__ q, u16* __restrict__ k, u16* __restrict__ vt)
{
    __shared__ __align__(16) u16 sA[128 * 64];
    __shared__ __align__(16) u16 sB[128 * 64];
    const int id = blockIdx.x;
    const int xcd = id & 7, slot = id >> 3;        // 192 slots per XCD
    const int m0 = (xcd * 8 + (slot & 7)) * 128;   // m-tile 0..63
    const int n0 = (slot >> 3) * 128;              // n-tile 0..23
    floatx4 acc[4][4];
    gemm_loop(x, Wcat, m0, n0, acc, sA, sB);

    const int tid = threadIdx.x;
    const int wave = tid >> 6, lane = tid & 63;
    const int wr = wave >> 1, wc = wave & 1;
    const int quad = lane >> 4, l15 = lane & 15;

    const int z = n0 >> 10;
    const float* bb = (z == 0) ? bq : (z == 1) ? bk : bv;
    const float scale = (z == 0) ? QSCALE : 1.0f;
    u16* o = (z == 0) ? q : k;

    #pragma unroll
    for (int nt = 0; nt < 4; ++nt) {
        int col  = n0 + wc * 64 + nt * 16 + l15;   // in [0,3072)
        int c    = col & 1023;
        float bv_ = bb[c];
        #pragma unroll
        for (int mt = 0; mt < 4; ++mt) {
            int row0 = m0 + wr * 64 + mt * 16 + quad * 4;
            if (z == 2) {
                // Vt: addr = ((b*16+h)*64+d)*2048 + t, t=row contiguous -> 8B store
                float v0 = acc[mt][nt][0] + bv_, v1 = acc[mt][nt][1] + bv_;
                float v2 = acc[mt][nt][2] + bv_, v3 = acc[mt][nt][3] + bv_;
                u32 dws[2] = { pkbf(v0, v1), pkbf(v2, v3) };
                int b = row0 >> 11, t0 = row0 & 2047;
                size_t idx = ((size_t)((b * 16 + (c >> 6)) * 64 + (c & 63)) * 2048) + t0;
                __builtin_memcpy(vt + idx, dws, 8);
            } else {
                #pragma unroll
                for (int r = 0; r < 4; ++r) {
                    float v = (acc[mt][nt][r] + bv_) * scale;
                    o[(size_t)(row0 + r) * 1024 + c] = f2b(v);
                }
            }
        }
    }
}

// ---------------- output projection ----------------
__global__ __launch_bounds__(256, 3) void proj_kernel(
    const u16* __restrict__ y, const u16* __restrict__ Wo, const float* __restrict__ bo,
    float* __restrict__ out)
{
    __shared__ __align__(16) u16 sA[128 * 64];
    __shared__ __align__(16) u16 sB[128 * 64];
    const int id = blockIdx.x;
    const int xcd = id & 7, slot = id >> 3;        // 64 slots per XCD
    const int m0 = (xcd * 8 + (slot & 7)) * 128;   // m-tile 0..63
    const int n0 = (slot >> 3) * 128;              // n-tile 0..7
    floatx4 acc[4][4];
    gemm_loop(y, Wo, m0, n0, acc, sA, sB);

    const int tid = threadIdx.x;
    const int wave = tid >> 6, lane = tid & 63;
    const int wr = wave >> 1, wc = wave & 1;
    const int quad = lane >> 4, l15 = lane & 15;

    #pragma unroll
    for (int nt = 0; nt < 4; ++nt) {
        int col = n0 + wc * 64 + nt * 16 + l15;
        float bv_ = bo[col];
        #pragma unroll
        for (int mt = 0; mt < 4; ++mt) {
            int row0 = m0 + wr * 64 + mt * 16 + quad * 4;
            #pragma unroll
            for (int r = 0; r < 4; ++r)
                out[(size_t)(row0 + r) * 1024 + col] = acc[mt][nt][r] + bv_;
        }
    }
}

// ---------------- Flash attention: r1 staging + cross-kt software pipeline (T15) ----------
// grid (bh=64, qt=8), block 256 = 4 waves, 2 blocks/CU. Wave owns 64 q-rows (nq=2).
// r15 post-mortem: prefetch guard was `t < 29`, so tile 31 was NEVER staged -> last
// step used stale K(29)/V(28) -> absmax 1.18e-2 (= one bad tile of 32). Fixed: t < 30.
// Core idea (unchanged): break the intra-wave S->exp->PV serial chain by pipelining S
// across kt: iteration t runs exp/pack/PV(t) (VALU, st in regs) while the matrix pipe
// digests S(t) (issued end of iter t-1) and S(t+1) (issued end of iter t).
// K double-buffered LDS (16KB), V TRIPLE-buffered (24KB, staging runs 2 tiles ahead).
// st ping-pong via named arrays + 2-step loop (rule #20: no runtime indexing).
// Buffer safety: slot written at iter t was last read at iter t-1; all ds_reads drain
// at each wave's barrier entry => one barrier per kt suffices.
// S^T = mfma_32x32x16(K, Q): C/D col=l31(q), row=(r&3)+8*(r>>2)+4*hf (k).
// P redistribution to PV B-frag = lane<->lane+32 at same l31 (T12).

#define S_TILE(stD, bK)                                                             \
    do {                                                                            \
        bf16x8 kfm[2][4];                                                           \
        _Pragma("unroll")                                                           \
        for (int m_ = 0; m_ < 2; ++m_) {                                            \
            const int row_ = m_ * 32 + l31;                                         \
            _Pragma("unroll")                                                       \
            for (int dc_ = 0; dc_ < 4; ++dc_)                                       \
                kfm[m_][dc_] = ld16B(&(bK)[row_ * 64 + (((dc_ * 2 + hf) ^ l7) * 8)]); \
        }                                                                           \
        __builtin_amdgcn_s_setprio(1);                                              \
        _Pragma("unroll")                                                           \
        for (int m_ = 0; m_ < 2; ++m_)                                              \
            _Pragma("unroll")                                                       \
            for (int nq_ = 0; nq_ < 2; ++nq_)                                       \
                stD[m_][nq_] = __builtin_amdgcn_mfma_f32_32x32x16_bf16(kfm[m_][0], qf[nq_][0], fz, 0, 0, 0); \
        _Pragma("unroll")                                                           \
        for (int dc_ = 1; dc_ < 4; ++dc_)                                           \
            _Pragma("unroll")                                                       \
            for (int m_ = 0; m_ < 2; ++m_)                                          \
                _Pragma("unroll")                                                   \
                for (int nq_ = 0; nq_ < 2; ++nq_)                                   \
                    stD[m_][nq_] = __builtin_amdgcn_mfma_f32_32x32x16_bf16(kfm[m_][dc_], qf[nq_][dc_], stD[m_][nq_], 0, 0, 0); \
        __builtin_amdgcn_s_setprio(0);                                              \
    } while (0)

#define EXP_PV(stP, bV)                                                             \
    do {                                                                            \
        bf16x8 vfm[2][4];                                                           \
        _Pragma("unroll")                                                           \
        for (int dt_ = 0; dt_ < 2; ++dt_) {                                         \
            const int row_ = dt_ * 32 + l31;                                        \
            _Pragma("unroll")                                                       \
            for (int c_ = 0; c_ < 4; ++c_)                                          \
                vfm[dt_][c_] = ld16B(&(bV)[row_ * 64 + (((c_ * 2 + hf) ^ l7) * 8)]); \
        }                                                                           \
        _Pragma("unroll")                                                           \
        for (int c_ = 0; c_ < 4; ++c_) {                                            \
            const int m_ = c_ >> 1, r0_ = (c_ & 1) * 8;                             \
            _Pragma("unroll")                                                       \
            for (int nq_ = 0; nq_ < 2; ++nq_) {                                     \
                float e0 = __builtin_amdgcn_exp2f(stP[m_][nq_][r0_ + 0]);           \
                float e1 = __builtin_amdgcn_exp2f(stP[m_][nq_][r0_ + 1]);           \
                float e2 = __builtin_amdgcn_exp2f(stP[m_][nq_][r0_ + 2]);           \
                float e3 = __builtin_amdgcn_exp2f(stP[m_][nq_][r0_ + 3]);           \
                float e4 = __builtin_amdgcn_exp2f(stP[m_][nq_][r0_ + 4]);           \
                float e5 = __builtin_amdgcn_exp2f(stP[m_][nq_][r0_ + 5]);           \
                float e6 = __builtin_amdgcn_exp2f(stP[m_][nq_][r0_ + 6]);           \
                float e7 = __builtin_amdgcn_exp2f(stP[m_][nq_][r0_ + 7]);           \
                accS[nq_] += ((e0 + e1) + (e2 + e3)) + ((e4 + e5) + (e6 + e7));     \
                u32 Ua = cvtpk(e0, e1), Ub = cvtpk(e2, e3);                         \
                u32 Va = cvtpk(e4, e5), Vb = cvtpk(e6, e7);                         \
                u32x2 s0 = __builtin_amdgcn_permlane32_swap(Ua, Va, false, false);  \
                u32x2 s1 = __builtin_amdgcn_permlane32_swap(Ub, Vb, false, false);  \
                u32 dws_[4] = { s0.x, s1.x, s0.y, s1.y };                           \
                bf16x8 pB; __builtin_memcpy(&pB, dws_, 16);                         \
                __builtin_amdgcn_s_setprio(1);                                      \
                accO[0][nq_] = __builtin_amdgcn_mfma_f32_32x32x16_bf16(vfm[0][c_], pB, accO[0][nq_], 0, 0, 0); \
                accO[1][nq_] = __builtin_amdgcn_mfma_f32_32x32x16_bf16(vfm[1][c_], pB, accO[1][nq_], 0, 0, 0); \
                __builtin_amdgcn_s_setprio(0);                                      \
            }                                                                       \
        }                                                                           \
    } while (0)

#define ATTN_STEP(stP, stN, t)                                                      \
    do {                                                                            \
        __syncthreads();        /* tile t+1 staged; prior reads of reused bufs done */ \
        if ((t) < 30) { stageK((t) + 2); stageV((t) + 2); }                         \
        EXP_PV(stP, sV + ((t) % 3) * 4096);                                         \
        S_TILE(stN, sK + (((t) + 1) & 1) * 4096);                                   \
    } while (0)

__global__ __launch_bounds__(256, 2) void attn_kernel(
    const u16* __restrict__ Q, const u16* __restrict__ K,
    const u16* __restrict__ Vt, u16* __restrict__ Y)
{
    const int bh = blockIdx.x, qt = blockIdx.y;
    const int tid = threadIdx.x;
    const int wave = tid >> 6, lane = tid & 63;
    const int hf = lane >> 5, l31 = lane & 31, l7 = l31 & 7;
    const int b = bh >> 4, h = bh & 15;

    // 40KB: K[2] x 8KB double buffer | V[3] x 8KB triple buffer. Epilogue reuses 32KB.
    __shared__ __align__(16) u16 smem[20480];
    u16* sK = smem;           // 2 * 4096 u16
    u16* sV = smem + 8192;    // 3 * 4096 u16

    // Q B-fragments (whole kernel in registers): qf[nq][dc]
    // B-frag: col=l31 (q row), k-dim d = dc*16 + hf*8 + j
    bf16x8 qf[2][4];
    {
        const size_t q0 = (size_t)(b * 2048 + qt * 256 + wave * 64) * 1024 + h * 64 + hf * 8;
        #pragma unroll
        for (int nq = 0; nq < 2; ++nq)
            #pragma unroll
            for (int dc = 0; dc < 4; ++dc)
                qf[nq][dc] = ld16B(Q + q0 + (size_t)(nq * 32 + l31) * 1024 + dc * 16);
    }

    const int r8 = lane >> 3;
    const int g7 = (lane & 7) ^ r8;                 // pre-swizzled global granule
    const u16* ksrc = K  + (size_t)(b * 2048 + wave * 16 + r8) * 1024 + h * 64 + g7 * 8;
    const u16* vsrc = Vt + ((size_t)(bh * 64 + wave * 16 + r8)) * 2048 + g7 * 8;

    auto stageK = [&](int t) {
        u16* dK = sK + (t & 1) * 4096 + wave * 1024;
        const u16* ks = ksrc + (size_t)t * 64 * 1024;
        async16(ks,            dK);
        async16(ks + 8 * 1024, dK + 512);
    };
    auto stageV = [&](int t) {
        u16* dV = sV + (t % 3) * 4096 + wave * 1024;
        const u16* vs = vsrc + (size_t)t * 64;
        async16(vs,            dV);
        async16(vs + 8 * 2048, dV + 512);
    };

    f32x16 accO[2][2];
    #pragma unroll
    for (int dt = 0; dt < 2; ++dt)
        #pragma unroll
        for (int nq = 0; nq < 2; ++nq)
            #pragma unroll
            for (int i = 0; i < 16; ++i) accO[dt][nq][i] = 0.f;
    float accS[2] = {0.f, 0.f};
    const f32x16 fz = {0.f,0.f,0.f,0.f,0.f,0.f,0.f,0.f,0.f,0.f,0.f,0.f,0.f,0.f,0.f,0.f};

    // prologue: tiles 0 and 1 staged; S(0) issued into stA
    stageK(0); stageV(0);
    __syncthreads();
    stageK(1); stageV(1);

    f32x16 stA[2][2], stB[2][2];
    S_TILE(stA, sK);   // K[0]

    // main pipeline: iter t = exp/PV(t) + S(t+1). 31 iterations, ping-pong st.
    #pragma unroll 1
    for (int t2 = 0; t2 < 30; t2 += 2) {
        ATTN_STEP(stA, stB, t2);
        ATTN_STEP(stB, stA, t2 + 1);
    }
    ATTN_STEP(stA, stB, 30);          // leaves st(31) in stB

    // drain: exp/PV(31). V(31) in slot 31%3=1, staged at t=29, drained at t=30 barrier.
    EXP_PV(stB, sV + (31 % 3) * 4096);

    // rowsum: lane holds k-halves with bit2==hf; partner is lane^32
    #pragma unroll
    for (int nq = 0; nq < 2; ++nq) accS[nq] += __shfl_xor(accS[nq], 32);
    const float inv0 = 1.f / accS[0], inv1 = 1.f / accS[1];

    __syncthreads();   // all waves done reading K/V buffers before smem reuse

    // epilogue: normalize, transpose O^T->O via per-wave 8KB LDS region
    u16* ep = smem + wave * 4096;   // 64 rows(q) x 64 cols(d), 16B-granule XOR swizzle
    #pragma unroll
    for (int nq = 0; nq < 2; ++nq) {
        const float inv = nq ? inv1 : inv0;
        const int row = nq * 32 + l31;
        #pragma unroll
        for (int dt = 0; dt < 2; ++dt)
            #pragma unroll
            for (int rq = 0; rq < 4; ++rq) {
                // accO reg r=rq*4+e -> d = dt*32 + rq*8 + 4*hf + e, q = row
                float v0 = accO[dt][nq][rq * 4 + 0] * inv;
                float v1 = accO[dt][nq][rq * 4 + 1] * inv;
                float v2 = accO[dt][nq][rq * 4 + 2] * inv;
                float v3 = accO[dt][nq][rq * 4 + 3] * inv;
                u32 dws[2] = { cvtpk(v0, v1), cvtpk(v2, v3) };
                const int g = dt * 4 + rq;
                __builtin_memcpy((char*)ep + row * 128 + ((g ^ l7) * 16) + hf * 8, dws, 8);
            }
    }
    // wave-private region: compiler orders ds write->read via lgkmcnt, no barrier needed
    const int rl = lane >> 3, cl = lane & 7;
    #pragma unroll
    for (int pass = 0; pass < 8; ++pass) {
        const int row = pass * 8 + rl;
        bf16x8 vrow = ld16B((const u16*)((const char*)ep + row * 128 + ((cl ^ (row & 7)) * 16)));
        const int t = qt * 256 + wave * 64 + row;
        __builtin_memcpy(Y + ((size_t)(b * 2048 + t)) * 1024 + h * 64 + cl * 8, &vrow, 16);
    }
}

// ---------------- launch ----------------
extern "C" void kernel_launch(void* const* d_in, const int* in_sizes, int n_in,
                              void* d_out, int out_size, void* d_ws, size_t ws_size,
                              hipStream_t stream)
{
    const float* x  = (const float*)d_in[0];
    const float* Wq = (const float*)d_in[1];
    const float* bq = (const float*)d_in[2];
    const float* Wk = (const float*)d_in[3];
    const float* bk = (const float*)d_in[4];
    const float* Wv = (const float*)d_in[5];
    const float* bv = (const float*)d_in[6];
    const float* Wo = (const float*)d_in[7];
    const float* bo = (const float*)d_in[8];
    float* out = (float*)d_out;

    const size_t NTOK = (size_t)8192 * 1024;
    const size_t WN   = (size_t)1024 * 1024;
    u16* xb  = (u16*)d_ws;
    u16* wqb = xb + NTOK;     // wq, wk, wv contiguous => [3072,1024] fused weight
    u16* wkb = wqb + WN;
    u16* wvb = wkb + WN;
    u16* wob = wvb + WN;
    u16* q   = wob + WN;
    u16* k   = q + NTOK;
    u16* vt  = k + NTOK;
    u16* y   = vt + NTOK;

    convert_kernel<<<dim3(12288), 256, 0, stream>>>(x, Wq, Wk, Wv, Wo, xb, wqb, wkb, wvb, wob);
    qkv_kernel<<<dim3(1536), 256, 0, stream>>>(xb, wqb, bq, bk, bv, q, k, vt);
    attn_kernel<<<dim3(64, 8), 256, 0, stream>>>(q, k, vt, y);
    proj_kernel<<<dim3(512), 256, 0, stream>>>(y, wob, bo, out);
}